// Round 3
// baseline (310.644 us; speedup 1.0000x reference)
//
#include <hip/hip_runtime.h>
#include <hip/hip_bf16.h>

#define DEV static __device__ __forceinline__

constexpr int B=16, N=128, FIN=128, FOUT=256, EOUT=64, BINW=14, BOUT=64, CI=64, L1=256;

// ---- workspace layout (float offsets), every region padded to 4-elem (16 B) ----
constexpr int HDR=16;
constexpr int O_X    = HDR;
constexpr int O_WE   = O_X + B*N*FIN;
constexpr int O_W    = O_WE + B*N*N*BINW;
constexpr int O_A    = O_W + FIN*FOUT;
constexpr int O_WFCW = O_A + 2*FOUT*EOUT;
constexpr int O_WFCB = O_WFCW + BINW*BOUT;
constexpr int O_FCW  = O_WFCB + BOUT;
constexpr int O_FCB  = O_FCW + (EOUT+BOUT);
constexpr int O_FCCW = O_FCB + 4;
constexpr int O_FCCB = O_FCCW + FOUT;
constexpr int O_WIHF = O_FCCB + 4;
constexpr int O_WHHF = O_WIHF + CI*N;
constexpr int O_BIHF = O_WHHF + CI*CI;
constexpr int O_BHHF = O_BIHF + CI;
constexpr int O_WIHB = O_BHHF + CI;
constexpr int O_WHHB = O_WIHB + CI*N;
constexpr int O_BIHB = O_WHHB + CI*CI;
constexpr int O_BHHB = O_BIHB + CI;
constexpr int O_FCOW = O_BHHB + CI;
constexpr int O_FCOB = O_FCOW + (2*CI+FOUT)*L1;
constexpr int CONV_END = O_FCOB + L1;
constexpr int CONV_TOTAL = CONV_END - HDR;
constexpr int O_SCR = ((CONV_END+127)/128)*128;
constexpr int O_H   = O_SCR;                   // [B,N,FOUT]
constexpr int O_P   = O_H  + B*N*FOUT;         // [B,N,EOUT]
constexpr int O_Q   = O_P  + B*N*EOUT;
constexpr int O_S   = O_Q  + B*N*EOUT;         // [B,N]
constexpr int O_ATT = O_S  + B*N;              // [B,N,N]
constexpr int O_ZF  = O_ATT+ B*N*N;            // [B,N,CI]
constexpr int O_ZB  = O_ZF + B*N*CI;
constexpr int O_RF  = O_ZB + B*N*CI;
constexpr int O_RB  = O_RF + B*N*CI;
constexpr int O_H1  = O_RB + B*N*CI;           // [B,N,FOUT]

constexpr int NCONV=20;
__constant__ int CCUM[NCONV+1] = {
  0,
  O_WE-HDR, O_W-HDR, O_A-HDR, O_WFCW-HDR, O_WFCB-HDR, O_FCW-HDR, O_FCB-HDR,
  O_FCCW-HDR, O_FCCB-HDR, O_WIHF-HDR, O_WHHF-HDR, O_BIHF-HDR, O_BHHF-HDR,
  O_WIHB-HDR, O_WHHB-HDR, O_BIHB-HDR, O_BHHB-HDR, O_FCOW-HDR, O_FCOB-HDR,
  CONV_TOTAL
};
__constant__ int CSIZE[NCONV] = {
  B*N*FIN, B*N*N*BINW, FIN*FOUT, 2*FOUT*EOUT, BINW*BOUT, BOUT, EOUT+BOUT, 1,
  FOUT, 1, CI*N, CI*CI, CI, CI, CI*N, CI*CI, CI, CI, (2*CI+FOUT)*L1, L1
};

DEV float bf16_to_f32(unsigned short u){
  unsigned int x = ((unsigned int)u) << 16; float f;
  __builtin_memcpy(&f, &x, 4); return f;
}
DEV float lrelu(float x){ return x > 0.f ? x : 0.01f * x; }

DEV int detect_bf16(const void* x){
  const unsigned short* u = (const unsigned short*)x;
  int cnt = 0;
  for (int k = 0; k < 128; ++k){
    int e = (u[k] >> 7) & 0xFF;
    if (e >= 100 && e <= 140) cnt++;
  }
  return cnt >= 110;
}

struct ConvArgs { const void* p[NCONV]; };

// K0: convert every float input to f32, contiguous (padded) in ws
__global__ __launch_bounds__(256) void k_convert(ConvArgs a, float* ws){
  __shared__ int smode;
  if (threadIdx.x == 0) smode = detect_bf16(a.p[0]);
  __syncthreads();
  int mode = smode;
  for (int gid = blockIdx.x*256 + threadIdx.x; gid < CONV_TOTAL; gid += gridDim.x*256){
    int t = 0;
    while (gid >= CCUM[t+1]) t++;
    int local = gid - CCUM[t];
    float v = 0.f;
    if (local < CSIZE[t])
      v = mode ? bf16_to_f32(((const unsigned short*)a.p[t])[local])
               : ((const float*)a.p[t])[local];
    ws[HDR + gid] = v;
  }
}

// K1: h = x@W ; s = h·fcc_w ; P = h@a_top ; Q = h@a_bot   (8 rows per block)
__global__ __launch_bounds__(256) void k_h_pq(const float* __restrict__ R, float* __restrict__ Wr){
  int blk = blockIdx.x, tid = threadIdx.x;
  int b = blk >> 4, i0 = (blk & 15) * 8;
  __shared__ __align__(16) float xl[8*FIN];
  __shared__ __align__(16) float hrow[8*FOUT];
  __shared__ float red[32];
  for (int t4 = tid; t4 < 8*FIN/4; t4 += 256)
    *(float4*)&xl[t4*4] = *(const float4*)&R[O_X + (b*N + i0)*FIN + t4*4];
  __syncthreads();
  int f = tid;
  float acc[8] = {0,0,0,0,0,0,0,0};
  for (int c = 0; c < FIN; c += 4){
    float w0 = R[O_W + (c+0)*FOUT + f];
    float w1 = R[O_W + (c+1)*FOUT + f];
    float w2 = R[O_W + (c+2)*FOUT + f];
    float w3 = R[O_W + (c+3)*FOUT + f];
    #pragma unroll
    for (int r = 0; r < 8; ++r){
      float4 x4 = *(const float4*)&xl[r*FIN + c];
      acc[r] += x4.x*w0 + x4.y*w1 + x4.z*w2 + x4.w*w3;
    }
  }
  float fw = R[O_FCCW + f];
  #pragma unroll
  for (int r = 0; r < 8; ++r){
    Wr[O_H + (b*N + i0 + r)*FOUT + f] = acc[r];
    hrow[r*FOUT + f] = acc[r];
  }
  #pragma unroll
  for (int r = 0; r < 8; ++r){
    float v = acc[r] * fw;
    for (int off = 32; off; off >>= 1) v += __shfl_down(v, off);
    if ((tid & 63) == 0) red[(tid >> 6)*8 + r] = v;
  }
  __syncthreads();
  if (tid < 8){
    float s = red[0*8+tid] + red[1*8+tid] + red[2*8+tid] + red[3*8+tid];
    Wr[O_S + b*N + i0 + tid] = s;
  }
  // P/Q: 4 waves = (which, half-of-rows); per-wave uniform LDS reads (broadcast)
  {
    int o = tid & 63, which = (tid >> 6) & 1, hh = tid >> 7;
    float a4[4] = {0.f,0.f,0.f,0.f};
    for (int c = 0; c < FOUT; c += 4){
      float w0 = R[O_A + (which*FOUT + c+0)*EOUT + o];
      float w1 = R[O_A + (which*FOUT + c+1)*EOUT + o];
      float w2 = R[O_A + (which*FOUT + c+2)*EOUT + o];
      float w3 = R[O_A + (which*FOUT + c+3)*EOUT + o];
      #pragma unroll
      for (int r = 0; r < 4; ++r){
        float4 h4 = *(const float4*)&hrow[(hh*4+r)*FOUT + c];
        a4[r] += h4.x*w0 + h4.y*w1 + h4.z*w2 + h4.w*w3;
      }
    }
    int ob = which ? O_Q : O_P;
    #pragma unroll
    for (int r = 0; r < 4; ++r)
      Wr[ob + (b*N + i0 + hh*4 + r)*EOUT + o] = a4[r];
  }
}

// K2: per (b,i): edge-MLP + su/sv (fused) + mask + softmax -> att ; z (RNN input)
__global__ __launch_bounds__(128) void k_att(const int* __restrict__ adj,
                                             const float* __restrict__ R,
                                             float* __restrict__ Wr){
  int blk = blockIdx.x; int b = blk >> 7, i = blk & 127; int tid = threadIdx.x;
  __shared__ __align__(16) float wel[N*BINW];
  __shared__ __align__(16) float attl[N];
  __shared__ __align__(16) float hnp[N];
  __shared__ float red2[2];
  __shared__ float sured[2];
  int base_we = (b*N + i)*N*BINW;
  for (int t4 = tid; t4 < N*BINW/4; t4 += 128)
    *(float4*)&wel[t4*4] = *(const float4*)&R[O_WE + base_we + t4*4];
  __syncthreads();
  int j = tid;
  float wr[BINW];
  #pragma unroll
  for (int t = 0; t < BINW; ++t) wr[t] = wel[j*BINW + t];
  float wcon = 0.f;
  for (int o = 0; o < BOUT; ++o){
    float wp = R[O_WFCB + o];                 // uniform addresses -> scalarizable
    #pragma unroll
    for (int t = 0; t < BINW; ++t) wp += wr[t] * R[O_WFCW + t*BOUT + o];
    wcon += lrelu(wp) * R[O_FCW + EOUT + o];
  }
  // econ (fused former k_susv), block-uniform branch on i
  float econ;
  if (i < 64){
    int w = tid >> 6, o = tid & 63;
    int r = 2*i + w;
    float u = R[O_P + (b*N + r)*EOUT + o] + R[O_Q + (b*N + r)*EOUT + o];
    float t1 = lrelu(u) * R[O_FCW + o];
    for (int off = 32; off; off >>= 1) t1 += __shfl_down(t1, off);
    if (o == 0) sured[w] = t1;
    __syncthreads();
    econ = sured[tid >> 6];
  } else {
    int j2 = (2*j) & 127;
    float acc = 0.f;
    for (int o = 0; o < EOUT; o += 4){
      float4 p4 = *(const float4*)&R[O_P + (b*N + j2)*EOUT + o];
      float4 q4 = *(const float4*)&R[O_Q + (b*N + j2 + 1)*EOUT + o];
      float4 f4 = *(const float4*)&R[O_FCW + o];
      acc += lrelu(p4.x+q4.x)*f4.x + lrelu(p4.y+q4.y)*f4.y
           + lrelu(p4.z+q4.z)*f4.z + lrelu(p4.w+q4.w)*f4.w;
    }
    econ = acc;
  }
  float etot = econ + wcon + R[O_FCB];
  float m = (adj[(b*N + i)*N + j] > 0) ? etot : -9e15f;
  float mx = m;
  for (int off = 32; off; off >>= 1) mx = fmaxf(mx, __shfl_xor(mx, off));
  if ((tid & 63) == 0) red2[tid >> 6] = mx;
  __syncthreads();
  mx = fmaxf(red2[0], red2[1]);
  float ev = expf(m - mx);
  float sum = ev;
  for (int off = 32; off; off >>= 1) sum += __shfl_xor(sum, off);
  __syncthreads();
  if ((tid & 63) == 0) red2[tid >> 6] = sum;
  __syncthreads();
  sum = red2[0] + red2[1];
  float att = ev / sum;
  attl[j] = att;
  Wr[O_ATT + (b*N + i)*N + j] = att;
  float sbi = R[O_S + b*N + i];
  hnp[j] = lrelu(att * sbi + R[O_FCCB]);
  __syncthreads();
  // z[b,i,c] both directions
  {
    int d = tid >> 6, c = tid & 63;
    int wb = d ? O_WIHB : O_WIHF;
    float acc = R[(d ? O_BIHB : O_BIHF) + c] + R[(d ? O_BHHB : O_BHHF) + c];
    #pragma unroll 8
    for (int k = 0; k < N; k += 4){
      float4 h4 = *(const float4*)&hnp[k];
      float4 w4 = *(const float4*)&R[wb + c*N + k];
      acc += h4.x*w4.x + h4.y*w4.y + h4.z*w4.z + h4.w*w4.w;
    }
    Wr[(d ? O_ZB : O_ZF) + (b*N + i)*CI + c] = acc;
  }
}

// K3: recurrence — one wave per (dir,batch); h broadcast via uniform ds_read_b128
// (single wave: DS ops are in-order per wave, so no barriers; no SGPR readlane hazards)
__global__ __launch_bounds__(64) void k_rnn(float* __restrict__ ws){
  int blk = blockIdx.x; int d = blk >> 4, b = blk & 15; int c = threadIdx.x;
  const int wb = d ? O_WHHB : O_WHHF;
  const int zb = d ? O_ZB : O_ZF;
  const int ob = d ? O_RB : O_RF;
  __shared__ __align__(16) float hl[CI];
  float wreg[CI];
  #pragma unroll
  for (int k = 0; k < CI; k += 4){
    float4 w4 = *(const float4*)&ws[wb + c*CI + k];
    wreg[k]=w4.x; wreg[k+1]=w4.y; wreg[k+2]=w4.z; wreg[k+3]=w4.w;
  }
  const int step = d ? -1 : 1;
  int tt = d ? (N-1) : 0;
  hl[c] = 0.f;
  // 2-deep z prefetch
  float z0 = ws[zb + (b*N + tt)*CI + c];
  float z1 = ws[zb + (b*N + tt + step)*CI + c];
  for (int t = 0; t < N; ++t){
    float z = z0;
    z0 = z1;
    int ti = tt + 2*step; ti = ti < 0 ? 0 : (ti > N-1 ? N-1 : ti);
    z1 = ws[zb + (b*N + ti)*CI + c];
    float a0 = z, a1 = 0.f, a2 = 0.f, a3 = 0.f;
    #pragma unroll
    for (int k = 0; k < CI; k += 4){
      float4 h4 = *(const float4*)&hl[k];   // uniform address -> LDS broadcast
      a0 = fmaf(h4.x, wreg[k+0], a0);
      a1 = fmaf(h4.y, wreg[k+1], a1);
      a2 = fmaf(h4.z, wreg[k+2], a2);
      a3 = fmaf(h4.w, wreg[k+3], a3);
    }
    float x = (a0+a1)+(a2+a3);
    x = fminf(15.f, fmaxf(-15.f, x));
    float p = __expf(2.f * x);
    float hv = (p - 1.f) * __builtin_amdgcn_rcpf(p + 1.f);
    hl[c] = hv;                              // in-order DS: safe for next iter
    ws[ob + (b*N + tt)*CI + c] = hv;
    tt += step;
  }
}

// K4: h1 = att @ h, 8 rows per block for h-tile reuse
__global__ __launch_bounds__(256) void k_h1(const float* __restrict__ R, float* __restrict__ Wr){
  int b = blockIdx.x >> 4, i0 = (blockIdx.x & 15) * 8;
  int f = threadIdx.x;
  __shared__ __align__(16) float attT[N*8];   // [k][r]
  for (int t = threadIdx.x; t < 8*N; t += 256){
    int r = t >> 7, k = t & 127;
    attT[k*8 + r] = R[O_ATT + (b*N + i0 + r)*N + k];
  }
  __syncthreads();
  float acc[8] = {0,0,0,0,0,0,0,0};
  for (int k = 0; k < N; ++k){
    float hv = R[O_H + (b*N + k)*FOUT + f];
    float4 a0 = *(const float4*)&attT[k*8];
    float4 a1 = *(const float4*)&attT[k*8 + 4];
    acc[0] += a0.x*hv; acc[1] += a0.y*hv; acc[2] += a0.z*hv; acc[3] += a0.w*hv;
    acc[4] += a1.x*hv; acc[5] += a1.y*hv; acc[6] += a1.z*hv; acc[7] += a1.w*hv;
  }
  #pragma unroll
  for (int r = 0; r < 8; ++r)
    Wr[O_H1 + (b*N + i0 + r)*FOUT + f] = acc[r];
}

// K5: out = elu(cat(lrelu(rnn_f), lrelu(rnn_b), h1) @ fco_w + fco_b), 16 rows/block
__global__ __launch_bounds__(256) void k_out(const void* __restrict__ x0,
                                             const float* __restrict__ R, void* dout){
  int blk = blockIdx.x, tid = threadIdx.x;
  int b = blk >> 3, i0 = (blk & 7) * 16;
  constexpr int KW = 2*CI + FOUT;  // 416
  __shared__ __align__(16) float inl[16*KW];
  __shared__ int smode;
  if (tid == 0) smode = detect_bf16(x0);
  for (int t = tid; t < 16*KW; t += 256){
    int r = t / KW, k = t % KW;
    int row = b*N + i0 + r;
    float v;
    if (k < CI)        v = lrelu(R[O_RF + row*CI + k]);
    else if (k < 2*CI) v = lrelu(R[O_RB + row*CI + (k - CI)]);
    else               v = R[O_H1 + row*FOUT + (k - 2*CI)];
    inl[t] = v;
  }
  __syncthreads();
  int l = tid;
  float bias = R[O_FCOB + l];
  float acc[16];
  #pragma unroll
  for (int r = 0; r < 16; ++r) acc[r] = bias;
  for (int k = 0; k < KW; k += 4){
    float w0 = R[O_FCOW + (k+0)*L1 + l];
    float w1 = R[O_FCOW + (k+1)*L1 + l];
    float w2 = R[O_FCOW + (k+2)*L1 + l];
    float w3 = R[O_FCOW + (k+3)*L1 + l];
    #pragma unroll
    for (int r = 0; r < 16; ++r){
      float4 v = *(const float4*)&inl[r*KW + k];  // uniform -> LDS broadcast
      acc[r] += v.x*w0 + v.y*w1 + v.z*w2 + v.w*w3;
    }
  }
  int mode = smode;
  #pragma unroll
  for (int r = 0; r < 16; ++r){
    float o = acc[r] > 0.f ? acc[r] : expm1f(acc[r]);
    int idx = (b*N + i0 + r)*L1 + l;
    if (mode) ((__hip_bfloat16*)dout)[idx] = __float2bfloat16(o);
    else      ((float*)dout)[idx] = o;
  }
}

extern "C" void kernel_launch(void* const* d_in, const int* in_sizes, int n_in,
                              void* d_out, int out_size, void* d_ws, size_t ws_size,
                              hipStream_t stream){
  (void)in_sizes; (void)n_in; (void)out_size; (void)ws_size;
  float* ws = (float*)d_ws;
  ConvArgs ca;
  const int map[NCONV] = {0,2,3,4,5,6,7,8,9,10,11,12,13,14,15,16,17,18,19,20};
  for (int t = 0; t < NCONV; ++t) ca.p[t] = d_in[map[t]];
  hipLaunchKernelGGL(k_convert, dim3(2048), dim3(256), 0, stream, ca, ws);
  hipLaunchKernelGGL(k_h_pq,   dim3(256),  dim3(256), 0, stream, ws, ws);
  hipLaunchKernelGGL(k_att,    dim3(B*N),  dim3(128), 0, stream, (const int*)d_in[1], ws, ws);
  hipLaunchKernelGGL(k_rnn,    dim3(32),   dim3(64),  0, stream, ws);
  hipLaunchKernelGGL(k_h1,     dim3(256),  dim3(256), 0, stream, ws, ws);
  hipLaunchKernelGGL(k_out,    dim3(B*N/16), dim3(256), 0, stream, d_in[0], ws, d_out);
}

// Round 4
// 246.719 us; speedup vs baseline: 1.2591x; 1.2591x over previous
//
#include <hip/hip_runtime.h>
#include <hip/hip_bf16.h>

#define DEV static __device__ __forceinline__

constexpr int B=16, N=128, FIN=128, FOUT=256, EOUT=64, BINW=14, BOUT=64, CI=64, L1=256;

// ---- workspace layout (float offsets), every region padded to 4-elem (16 B) ----
constexpr int HDR=16;
constexpr int O_X    = HDR;
constexpr int O_WE   = O_X + B*N*FIN;
constexpr int O_W    = O_WE + B*N*N*BINW;
constexpr int O_A    = O_W + FIN*FOUT;
constexpr int O_WFCW = O_A + 2*FOUT*EOUT;
constexpr int O_WFCB = O_WFCW + BINW*BOUT;
constexpr int O_FCW  = O_WFCB + BOUT;
constexpr int O_FCB  = O_FCW + (EOUT+BOUT);
constexpr int O_FCCW = O_FCB + 4;
constexpr int O_FCCB = O_FCCW + FOUT;
constexpr int O_WIHF = O_FCCB + 4;
constexpr int O_WHHF = O_WIHF + CI*N;
constexpr int O_BIHF = O_WHHF + CI*CI;
constexpr int O_BHHF = O_BIHF + CI;
constexpr int O_WIHB = O_BHHF + CI;
constexpr int O_WHHB = O_WIHB + CI*N;
constexpr int O_BIHB = O_WHHB + CI*CI;
constexpr int O_BHHB = O_BIHB + CI;
constexpr int O_FCOW = O_BHHB + CI;
constexpr int O_FCOB = O_FCOW + (2*CI+FOUT)*L1;
constexpr int CONV_END = O_FCOB + L1;
constexpr int CONV_TOTAL = CONV_END - HDR;
constexpr int O_SCR = ((CONV_END+127)/128)*128;
constexpr int O_H   = O_SCR;                   // [B,N,FOUT]
constexpr int O_P   = O_H  + B*N*FOUT;         // [B,N,EOUT]
constexpr int O_Q   = O_P  + B*N*EOUT;
constexpr int O_S   = O_Q  + B*N*EOUT;         // [B,N]
constexpr int O_SU  = O_S  + B*N;
constexpr int O_SV  = O_SU + B*N;
constexpr int O_ATT = O_SV + B*N;              // [B,N,N]
constexpr int O_ZF  = O_ATT+ B*N*N;            // [B,N,CI]
constexpr int O_ZB  = O_ZF + B*N*CI;
constexpr int O_RF  = O_ZB + B*N*CI;
constexpr int O_RB  = O_RF + B*N*CI;
constexpr int O_H1  = O_RB + B*N*CI;           // [B,N,FOUT]

constexpr int NCONV=20;
__constant__ int CCUM[NCONV+1] = {
  0,
  O_WE-HDR, O_W-HDR, O_A-HDR, O_WFCW-HDR, O_WFCB-HDR, O_FCW-HDR, O_FCB-HDR,
  O_FCCW-HDR, O_FCCB-HDR, O_WIHF-HDR, O_WHHF-HDR, O_BIHF-HDR, O_BHHF-HDR,
  O_WIHB-HDR, O_WHHB-HDR, O_BIHB-HDR, O_BHHB-HDR, O_FCOW-HDR, O_FCOB-HDR,
  CONV_TOTAL
};
__constant__ int CSIZE[NCONV] = {
  B*N*FIN, B*N*N*BINW, FIN*FOUT, 2*FOUT*EOUT, BINW*BOUT, BOUT, EOUT+BOUT, 1,
  FOUT, 1, CI*N, CI*CI, CI, CI, CI*N, CI*CI, CI, CI, (2*CI+FOUT)*L1, L1
};

DEV float bf16_to_f32(unsigned short u){
  unsigned int x = ((unsigned int)u) << 16; float f;
  __builtin_memcpy(&f, &x, 4); return f;
}
DEV float lrelu(float x){ return x > 0.f ? x : 0.01f * x; }

DEV int detect_bf16(const void* x){
  const unsigned short* u = (const unsigned short*)x;
  int cnt = 0;
  for (int k = 0; k < 128; ++k){
    int e = (u[k] >> 7) & 0xFF;
    if (e >= 100 && e <= 140) cnt++;
  }
  return cnt >= 110;
}

struct ConvArgs { const void* p[NCONV]; };

// K0: convert every float input to f32, contiguous (padded) in ws
__global__ __launch_bounds__(256) void k_convert(ConvArgs a, float* ws){
  __shared__ int smode;
  if (threadIdx.x == 0) smode = detect_bf16(a.p[0]);
  __syncthreads();
  int mode = smode;
  for (int gid = blockIdx.x*256 + threadIdx.x; gid < CONV_TOTAL; gid += gridDim.x*256){
    int t = 0;
    while (gid >= CCUM[t+1]) t++;
    int local = gid - CCUM[t];
    float v = 0.f;
    if (local < CSIZE[t])
      v = mode ? bf16_to_f32(((const unsigned short*)a.p[t])[local])
               : ((const float*)a.p[t])[local];
    ws[HDR + gid] = v;
  }
}

// K1: h = x@W ; s = h·fcc_w ; P = h@a_top ; Q = h@a_bot   (8 rows per block)
__global__ __launch_bounds__(256) void k_h_pq(const float* __restrict__ R, float* __restrict__ Wr){
  int blk = blockIdx.x, tid = threadIdx.x;
  int b = blk >> 4, i0 = (blk & 15) * 8;
  __shared__ __align__(16) float xl[8*FIN];
  __shared__ __align__(16) float hrow[8*FOUT];
  __shared__ float red[32];
  for (int t4 = tid; t4 < 8*FIN/4; t4 += 256)
    *(float4*)&xl[t4*4] = *(const float4*)&R[O_X + (b*N + i0)*FIN + t4*4];
  __syncthreads();
  int f = tid;
  float acc[8] = {0,0,0,0,0,0,0,0};
  for (int c = 0; c < FIN; c += 4){
    float w0 = R[O_W + (c+0)*FOUT + f];
    float w1 = R[O_W + (c+1)*FOUT + f];
    float w2 = R[O_W + (c+2)*FOUT + f];
    float w3 = R[O_W + (c+3)*FOUT + f];
    #pragma unroll
    for (int r = 0; r < 8; ++r){
      float4 x4 = *(const float4*)&xl[r*FIN + c];
      acc[r] += x4.x*w0 + x4.y*w1 + x4.z*w2 + x4.w*w3;
    }
  }
  float fw = R[O_FCCW + f];
  #pragma unroll
  for (int r = 0; r < 8; ++r){
    Wr[O_H + (b*N + i0 + r)*FOUT + f] = acc[r];
    hrow[r*FOUT + f] = acc[r];
  }
  #pragma unroll
  for (int r = 0; r < 8; ++r){
    float v = acc[r] * fw;
    for (int off = 32; off; off >>= 1) v += __shfl_down(v, off);
    if ((tid & 63) == 0) red[(tid >> 6)*8 + r] = v;
  }
  __syncthreads();
  if (tid < 8){
    float s = red[0*8+tid] + red[1*8+tid] + red[2*8+tid] + red[3*8+tid];
    Wr[O_S + b*N + i0 + tid] = s;
  }
  // P/Q: 4 waves = (which, half-of-rows); per-wave uniform LDS reads (broadcast)
  {
    int o = tid & 63, which = (tid >> 6) & 1, hh = tid >> 7;
    float a4[4] = {0.f,0.f,0.f,0.f};
    for (int c = 0; c < FOUT; c += 4){
      float w0 = R[O_A + (which*FOUT + c+0)*EOUT + o];
      float w1 = R[O_A + (which*FOUT + c+1)*EOUT + o];
      float w2 = R[O_A + (which*FOUT + c+2)*EOUT + o];
      float w3 = R[O_A + (which*FOUT + c+3)*EOUT + o];
      #pragma unroll
      for (int r = 0; r < 4; ++r){
        float4 h4 = *(const float4*)&hrow[(hh*4+r)*FOUT + c];
        a4[r] += h4.x*w0 + h4.y*w1 + h4.z*w2 + h4.w*w3;
      }
    }
    int ob = which ? O_Q : O_P;
    #pragma unroll
    for (int r = 0; r < 4; ++r)
      Wr[ob + (b*N + i0 + hh*4 + r)*EOUT + o] = a4[r];
  }
}

// K2: su/sv scalars
__global__ __launch_bounds__(64) void k_susv(const float* __restrict__ R, float* __restrict__ Wr){
  int blk = blockIdx.x; int b = blk >> 7, r = blk & 127; int o = threadIdx.x;
  float fw = R[O_FCW + o];
  float u = R[O_P + (b*N + r)*EOUT + o] + R[O_Q + (b*N + r)*EOUT + o];
  float t1 = lrelu(u) * fw;
  int j2 = (2*r) & 127;
  float v = R[O_P + (b*N + j2)*EOUT + o] + R[O_Q + (b*N + j2 + 1)*EOUT + o];
  float t2 = lrelu(v) * fw;
  for (int off = 32; off; off >>= 1){ t1 += __shfl_down(t1, off); t2 += __shfl_down(t2, off); }
  if (o == 0){ Wr[O_SU + b*N + r] = t1; Wr[O_SV + b*N + r] = t2; }
}

// K3: per (b,i): edge-MLP + mask + softmax -> att (stored) ; hn_pre ; z (RNN input)
__global__ __launch_bounds__(128) void k_att(const int* __restrict__ adj,
                                             const float* __restrict__ R,
                                             float* __restrict__ Wr){
  int blk = blockIdx.x; int b = blk >> 7, i = blk & 127; int tid = threadIdx.x;
  __shared__ __align__(16) float wel[N*BINW];
  __shared__ __align__(16) float attl[N];
  __shared__ __align__(16) float hnp[N];
  __shared__ float red2[2];
  int base_we = (b*N + i)*N*BINW;
  for (int t4 = tid; t4 < N*BINW/4; t4 += 128)
    *(float4*)&wel[t4*4] = *(const float4*)&R[O_WE + base_we + t4*4];
  __syncthreads();
  int j = tid;
  float wr[BINW];
  #pragma unroll
  for (int t = 0; t < BINW; ++t) wr[t] = wel[j*BINW + t];
  float wcon = 0.f;
  for (int o = 0; o < BOUT; ++o){
    float wp = R[O_WFCB + o];                 // uniform addresses -> scalarizable
    #pragma unroll
    for (int t = 0; t < BINW; ++t) wp += wr[t] * R[O_WFCW + t*BOUT + o];
    wcon += lrelu(wp) * R[O_FCW + EOUT + o];
  }
  float econ = (i < 64) ? R[O_SU + b*N + 2*i + (j >= 64 ? 1 : 0)]
                        : R[O_SV + b*N + j];
  float etot = econ + wcon + R[O_FCB];
  float m = (adj[(b*N + i)*N + j] > 0) ? etot : -9e15f;
  float mx = m;
  for (int off = 32; off; off >>= 1) mx = fmaxf(mx, __shfl_xor(mx, off));
  if ((tid & 63) == 0) red2[tid >> 6] = mx;
  __syncthreads();
  mx = fmaxf(red2[0], red2[1]);
  float ev = expf(m - mx);
  float sum = ev;
  for (int off = 32; off; off >>= 1) sum += __shfl_xor(sum, off);
  __syncthreads();
  if ((tid & 63) == 0) red2[tid >> 6] = sum;
  __syncthreads();
  sum = red2[0] + red2[1];
  float att = ev / sum;
  attl[j] = att;
  Wr[O_ATT + (b*N + i)*N + j] = att;
  float sbi = R[O_S + b*N + i];
  hnp[j] = lrelu(att * sbi + R[O_FCCB]);
  __syncthreads();
  // z[b,i,c] both directions
  {
    int d = tid >> 6, c = tid & 63;
    int wb = d ? O_WIHB : O_WIHF;
    float acc = R[(d ? O_BIHB : O_BIHF) + c] + R[(d ? O_BHHB : O_BHHF) + c];
    #pragma unroll 8
    for (int k = 0; k < N; k += 4){
      float4 h4 = *(const float4*)&hnp[k];
      float4 w4 = *(const float4*)&R[wb + c*N + k];
      acc += h4.x*w4.x + h4.y*w4.y + h4.z*w4.z + h4.w*w4.w;
    }
    Wr[(d ? O_ZB : O_ZF) + (b*N + i)*CI + c] = acc;
  }
}

// K4: recurrence — one wave per (dir,batch); the time loop is 100% LDS+VALU
// (z staged into LDS up front, outputs written back into the same buffer,
//  dumped to global after the loop; no VMEM waits inside the chain)
__global__ __launch_bounds__(64) void k_rnn(float* __restrict__ ws){
  int blk = blockIdx.x; int d = blk >> 4, b = blk & 15; int c = threadIdx.x;
  const int wb = d ? O_WHHB : O_WHHF;
  const int zb = (d ? O_ZB : O_ZF) + b*N*CI;
  const int ob = (d ? O_RB : O_RF) + b*N*CI;
  __shared__ __align__(16) float zo[N*CI];   // 32 KB: z in / h out (slot t dead after step t)
  __shared__ __align__(16) float hl[CI];
  float wreg[CI];
  #pragma unroll
  for (int k = 0; k < CI; k += 4){
    float4 w4 = *(const float4*)&ws[wb + c*CI + k];
    wreg[k]=w4.x; wreg[k+1]=w4.y; wreg[k+2]=w4.z; wreg[k+3]=w4.w;
  }
  for (int it = 0; it < N*CI/4; it += 64)
    *(float4*)&zo[(it + c)*4] = *(const float4*)&ws[zb + (it + c)*4];
  hl[c] = 0.f;
  __syncthreads();
  const int step = d ? -1 : 1;
  int tt = d ? (N-1) : 0;
  for (int t = 0; t < N; ++t){
    float z = zo[tt*CI + c];
    float a0 = z, a1 = 0.f, a2 = 0.f, a3 = 0.f;
    #pragma unroll
    for (int k = 0; k < CI; k += 4){
      float4 h4 = *(const float4*)&hl[k];   // uniform address -> LDS broadcast
      a0 = fmaf(h4.x, wreg[k+0], a0);
      a1 = fmaf(h4.y, wreg[k+1], a1);
      a2 = fmaf(h4.z, wreg[k+2], a2);
      a3 = fmaf(h4.w, wreg[k+3], a3);
    }
    float x = (a0+a1)+(a2+a3);
    x = fminf(15.f, fmaxf(-15.f, x));
    float p = __expf(2.f * x);
    float hv = (p - 1.f) * __builtin_amdgcn_rcpf(p + 1.f);
    hl[c] = hv;                 // single wave: DS ops in order, no barrier needed
    zo[tt*CI + c] = hv;
    tt += step;
  }
  for (int it = 0; it < N*CI/4; it += 64)
    *(float4*)&ws[ob + (it + c)*4] = *(const float4*)&zo[(it + c)*4];
}

// K5: h1 = att @ h, 8 rows per block for h-tile reuse
__global__ __launch_bounds__(256) void k_h1(const float* __restrict__ R, float* __restrict__ Wr){
  int b = blockIdx.x >> 4, i0 = (blockIdx.x & 15) * 8;
  int f = threadIdx.x;
  __shared__ __align__(16) float attT[N*8];   // [k][r]
  for (int t = threadIdx.x; t < 8*N; t += 256){
    int r = t >> 7, k = t & 127;
    attT[k*8 + r] = R[O_ATT + (b*N + i0 + r)*N + k];
  }
  __syncthreads();
  float acc[8] = {0,0,0,0,0,0,0,0};
  for (int k = 0; k < N; ++k){
    float hv = R[O_H + (b*N + k)*FOUT + f];
    float4 a0 = *(const float4*)&attT[k*8];
    float4 a1 = *(const float4*)&attT[k*8 + 4];
    acc[0] += a0.x*hv; acc[1] += a0.y*hv; acc[2] += a0.z*hv; acc[3] += a0.w*hv;
    acc[4] += a1.x*hv; acc[5] += a1.y*hv; acc[6] += a1.z*hv; acc[7] += a1.w*hv;
  }
  #pragma unroll
  for (int r = 0; r < 8; ++r)
    Wr[O_H1 + (b*N + i0 + r)*FOUT + f] = acc[r];
}

// K6: out = elu(cat(lrelu(rnn_f), lrelu(rnn_b), h1) @ fco_w + fco_b), 4 rows/block
__global__ __launch_bounds__(256) void k_out(const void* __restrict__ x0,
                                             const float* __restrict__ R, void* dout){
  int blk = blockIdx.x, tid = threadIdx.x;
  int b = blk >> 5, i0 = (blk & 31) * 4;
  constexpr int KW = 2*CI + FOUT;  // 416
  __shared__ __align__(16) float inl[4*KW];
  __shared__ int smode;
  if (tid == 0) smode = detect_bf16(x0);
  for (int t = tid; t < 4*KW; t += 256){
    int r = t / KW, k = t % KW;
    int row = b*N + i0 + r;
    float v;
    if (k < CI)        v = lrelu(R[O_RF + row*CI + k]);
    else if (k < 2*CI) v = lrelu(R[O_RB + row*CI + (k - CI)]);
    else               v = R[O_H1 + row*FOUT + (k - 2*CI)];
    inl[t] = v;
  }
  __syncthreads();
  int l = tid;
  float bias = R[O_FCOB + l];
  float acc[4] = {bias, bias, bias, bias};
  for (int k = 0; k < KW; k += 4){
    float w0 = R[O_FCOW + (k+0)*L1 + l];
    float w1 = R[O_FCOW + (k+1)*L1 + l];
    float w2 = R[O_FCOW + (k+2)*L1 + l];
    float w3 = R[O_FCOW + (k+3)*L1 + l];
    #pragma unroll
    for (int r = 0; r < 4; ++r){
      float4 v = *(const float4*)&inl[r*KW + k];
      acc[r] += v.x*w0 + v.y*w1 + v.z*w2 + v.w*w3;
    }
  }
  int mode = smode;
  #pragma unroll
  for (int r = 0; r < 4; ++r){
    float o = acc[r] > 0.f ? acc[r] : expm1f(acc[r]);
    int idx = (b*N + i0 + r)*L1 + l;
    if (mode) ((__hip_bfloat16*)dout)[idx] = __float2bfloat16(o);
    else      ((float*)dout)[idx] = o;
  }
}

extern "C" void kernel_launch(void* const* d_in, const int* in_sizes, int n_in,
                              void* d_out, int out_size, void* d_ws, size_t ws_size,
                              hipStream_t stream){
  (void)in_sizes; (void)n_in; (void)out_size; (void)ws_size;
  float* ws = (float*)d_ws;
  ConvArgs ca;
  const int map[NCONV] = {0,2,3,4,5,6,7,8,9,10,11,12,13,14,15,16,17,18,19,20};
  for (int t = 0; t < NCONV; ++t) ca.p[t] = d_in[map[t]];
  hipLaunchKernelGGL(k_convert, dim3(2048), dim3(256), 0, stream, ca, ws);
  hipLaunchKernelGGL(k_h_pq,   dim3(256),  dim3(256), 0, stream, ws, ws);
  hipLaunchKernelGGL(k_susv,   dim3(B*N),  dim3(64),  0, stream, ws, ws);
  hipLaunchKernelGGL(k_att,    dim3(B*N),  dim3(128), 0, stream, (const int*)d_in[1], ws, ws);
  hipLaunchKernelGGL(k_rnn,    dim3(32),   dim3(64),  0, stream, ws);
  hipLaunchKernelGGL(k_h1,     dim3(256),  dim3(256), 0, stream, ws, ws);
  hipLaunchKernelGGL(k_out,    dim3(B*N/4), dim3(256), 0, stream, d_in[0], ws, d_out);
}

// Round 5
// 233.615 us; speedup vs baseline: 1.3297x; 1.0561x over previous
//
#include <hip/hip_runtime.h>
#include <hip/hip_bf16.h>

#define DEV static __device__ __forceinline__

constexpr int B=16, N=128, FIN=128, FOUT=256, EOUT=64, BINW=14, BOUT=64, CI=64, L1=256;

// ---- workspace layout (float offsets), every region padded to 4-elem (16 B) ----
constexpr int HDR=16;
constexpr int O_X    = HDR;                    // unused (x converted inline)
constexpr int O_WE   = O_X + B*N*FIN;          // unused (w_edge converted inline)
constexpr int O_W    = O_WE + B*N*N*BINW;
constexpr int O_A    = O_W + FIN*FOUT;
constexpr int O_WFCW = O_A + 2*FOUT*EOUT;
constexpr int O_WFCB = O_WFCW + BINW*BOUT;
constexpr int O_FCW  = O_WFCB + BOUT;
constexpr int O_FCB  = O_FCW + (EOUT+BOUT);
constexpr int O_FCCW = O_FCB + 4;
constexpr int O_FCCB = O_FCCW + FOUT;
constexpr int O_WIHF = O_FCCB + 4;
constexpr int O_WHHF = O_WIHF + CI*N;
constexpr int O_BIHF = O_WHHF + CI*CI;
constexpr int O_BHHF = O_BIHF + CI;
constexpr int O_WIHB = O_BHHF + CI;
constexpr int O_WHHB = O_WIHB + CI*N;
constexpr int O_BIHB = O_WHHB + CI*CI;
constexpr int O_BHHB = O_BIHB + CI;
constexpr int O_FCOW = O_BHHB + CI;
constexpr int O_FCOB = O_FCOW + (2*CI+FOUT)*L1;
constexpr int CONV_END = O_FCOB + L1;
constexpr int O_SCR = ((CONV_END+127)/128)*128;
constexpr int O_H   = O_SCR;                   // [B,N,FOUT]
constexpr int O_P   = O_H  + B*N*FOUT;         // [B,N,EOUT]
constexpr int O_Q   = O_P  + B*N*EOUT;
constexpr int O_S   = O_Q  + B*N*EOUT;         // [B,N]
constexpr int O_SU  = O_S  + B*N;
constexpr int O_SV  = O_SU + B*N;
constexpr int O_ATT = O_SV + B*N;              // [B,N,N]
constexpr int O_ZF  = O_ATT+ B*N*N;            // [B,N,CI]
constexpr int O_ZB  = O_ZF + B*N*CI;
constexpr int O_RF  = O_ZB + B*N*CI;
constexpr int O_RB  = O_RF + B*N*CI;
constexpr int O_H1  = O_RB + B*N*CI;           // [B,N,FOUT]

// ---- k_convert: weights only (x, w_edge converted inline by consumers) ----
constexpr int NCONV=18;
constexpr int CONV_N=198466;
__constant__ int OBASE[NCONV] = {
  O_W,O_A,O_WFCW,O_WFCB,O_FCW,O_FCB,O_FCCW,O_FCCB,
  O_WIHF,O_WHHF,O_BIHF,O_BHHF,O_WIHB,O_WHHB,O_BIHB,O_BHHB,O_FCOW,O_FCOB
};
__constant__ int CCUM[NCONV+1] = {
  0,32768,65536,66432,66496,66624,66625,66881,66882,
  75074,79170,79234,79298,87490,91586,91650,91714,198210,198466
};

DEV float bf16_to_f32(unsigned short u){
  unsigned int x = ((unsigned int)u) << 16; float f;
  __builtin_memcpy(&f, &x, 4); return f;
}
DEV void bf2x(unsigned int u, float& lo, float& hi){
  unsigned int a = u << 16, b = u & 0xFFFF0000u;
  __builtin_memcpy(&lo, &a, 4); __builtin_memcpy(&hi, &b, 4);
}
DEV float lrelu(float x){ return x > 0.f ? x : 0.01f * x; }
DEV float bcastf(float v, int lane){
  return __builtin_bit_cast(float, __builtin_amdgcn_readlane(__builtin_bit_cast(int, v), lane));
}

DEV int detect_bf16(const void* x){
  const unsigned short* u = (const unsigned short*)x;
  int cnt = 0;
  for (int k = 0; k < 128; ++k){
    int e = (u[k] >> 7) & 0xFF;
    if (e >= 100 && e <= 140) cnt++;
  }
  return cnt >= 110;
}

struct ConvArgs { const void* p[NCONV]; };

// K0: convert weight tensors to f32 in ws
__global__ __launch_bounds__(256) void k_convert(ConvArgs a, const void* x0, float* ws){
  __shared__ int smode;
  if (threadIdx.x == 0) smode = detect_bf16(x0);
  __syncthreads();
  int mode = smode;
  for (int gid = blockIdx.x*256 + threadIdx.x; gid < CONV_N; gid += gridDim.x*256){
    int t = 0;
    while (gid >= CCUM[t+1]) t++;
    int local = gid - CCUM[t];
    float v = mode ? bf16_to_f32(((const unsigned short*)a.p[t])[local])
                   : ((const float*)a.p[t])[local];
    ws[OBASE[t] + local] = v;
  }
}

// K1: h = x@W ; s = h·fcc_w ; P = h@a_top ; Q = h@a_bot   (8 rows per block; x inline-converted)
__global__ __launch_bounds__(256) void k_h_pq(const void* __restrict__ x_raw,
                                              const float* __restrict__ R, float* __restrict__ Wr){
  int blk = blockIdx.x, tid = threadIdx.x;
  int b = blk >> 4, i0 = (blk & 15) * 8;
  __shared__ __align__(16) float xl[8*FIN];
  __shared__ __align__(16) float hrow[8*FOUT];
  __shared__ float red[32];
  __shared__ int smode;
  if (tid == 0) smode = detect_bf16(x_raw);
  __syncthreads();
  if (smode){
    const unsigned short* xu = (const unsigned short*)x_raw + (size_t)(b*N + i0)*FIN;
    for (int t = tid; t < 8*FIN/8; t += 256){
      uint4 u = ((const uint4*)xu)[t];
      float* o = &xl[t*8];
      bf2x(u.x, o[0], o[1]); bf2x(u.y, o[2], o[3]);
      bf2x(u.z, o[4], o[5]); bf2x(u.w, o[6], o[7]);
    }
  } else {
    const float* xf = (const float*)x_raw + (size_t)(b*N + i0)*FIN;
    for (int t4 = tid; t4 < 8*FIN/4; t4 += 256)
      *(float4*)&xl[t4*4] = *(const float4*)&xf[t4*4];
  }
  __syncthreads();
  int f = tid;
  float acc[8] = {0,0,0,0,0,0,0,0};
  for (int c = 0; c < FIN; c += 4){
    float w0 = R[O_W + (c+0)*FOUT + f];
    float w1 = R[O_W + (c+1)*FOUT + f];
    float w2 = R[O_W + (c+2)*FOUT + f];
    float w3 = R[O_W + (c+3)*FOUT + f];
    #pragma unroll
    for (int r = 0; r < 8; ++r){
      float4 x4 = *(const float4*)&xl[r*FIN + c];
      acc[r] += x4.x*w0 + x4.y*w1 + x4.z*w2 + x4.w*w3;
    }
  }
  float fw = R[O_FCCW + f];
  #pragma unroll
  for (int r = 0; r < 8; ++r){
    Wr[O_H + (b*N + i0 + r)*FOUT + f] = acc[r];
    hrow[r*FOUT + f] = acc[r];
  }
  #pragma unroll
  for (int r = 0; r < 8; ++r){
    float v = acc[r] * fw;
    for (int off = 32; off; off >>= 1) v += __shfl_down(v, off);
    if ((tid & 63) == 0) red[(tid >> 6)*8 + r] = v;
  }
  __syncthreads();
  if (tid < 8){
    float s = red[0*8+tid] + red[1*8+tid] + red[2*8+tid] + red[3*8+tid];
    Wr[O_S + b*N + i0 + tid] = s;
  }
  {
    int o = tid & 63, which = (tid >> 6) & 1, hh = tid >> 7;
    float a4[4] = {0.f,0.f,0.f,0.f};
    for (int c = 0; c < FOUT; c += 4){
      float w0 = R[O_A + (which*FOUT + c+0)*EOUT + o];
      float w1 = R[O_A + (which*FOUT + c+1)*EOUT + o];
      float w2 = R[O_A + (which*FOUT + c+2)*EOUT + o];
      float w3 = R[O_A + (which*FOUT + c+3)*EOUT + o];
      #pragma unroll
      for (int r = 0; r < 4; ++r){
        float4 h4 = *(const float4*)&hrow[(hh*4+r)*FOUT + c];
        a4[r] += h4.x*w0 + h4.y*w1 + h4.z*w2 + h4.w*w3;
      }
    }
    int ob = which ? O_Q : O_P;
    #pragma unroll
    for (int r = 0; r < 4; ++r)
      Wr[ob + (b*N + i0 + hh*4 + r)*EOUT + o] = a4[r];
  }
}

// K2: su/sv scalars
__global__ __launch_bounds__(64) void k_susv(const float* __restrict__ R, float* __restrict__ Wr){
  int blk = blockIdx.x; int b = blk >> 7, r = blk & 127; int o = threadIdx.x;
  float fw = R[O_FCW + o];
  float u = R[O_P + (b*N + r)*EOUT + o] + R[O_Q + (b*N + r)*EOUT + o];
  float t1 = lrelu(u) * fw;
  int j2 = (2*r) & 127;
  float v = R[O_P + (b*N + j2)*EOUT + o] + R[O_Q + (b*N + j2 + 1)*EOUT + o];
  float t2 = lrelu(v) * fw;
  for (int off = 32; off; off >>= 1){ t1 += __shfl_down(t1, off); t2 += __shfl_down(t2, off); }
  if (o == 0){ Wr[O_SU + b*N + r] = t1; Wr[O_SV + b*N + r] = t2; }
}

// K3: per (b,i): edge-MLP (w_edge inline-converted) + mask + softmax -> att ; hn_pre ; z
__global__ __launch_bounds__(128) void k_att(const int* __restrict__ adj,
                                             const void* __restrict__ we_raw,
                                             const void* __restrict__ x0,
                                             const float* __restrict__ R,
                                             float* __restrict__ Wr){
  int blk = blockIdx.x; int b = blk >> 7, i = blk & 127; int tid = threadIdx.x;
  __shared__ __align__(16) float wel[N*BINW];
  __shared__ __align__(16) float attl[N];
  __shared__ __align__(16) float hnp[N];
  __shared__ float red2[2];
  __shared__ int smode;
  if (tid == 0) smode = detect_bf16(x0);
  __syncthreads();
  if (smode){
    const unsigned short* weu = (const unsigned short*)we_raw + (size_t)(b*N + i)*N*BINW;
    for (int t = tid; t < N*BINW/8; t += 128){
      uint4 u = ((const uint4*)weu)[t];
      float* o = &wel[t*8];
      bf2x(u.x, o[0], o[1]); bf2x(u.y, o[2], o[3]);
      bf2x(u.z, o[4], o[5]); bf2x(u.w, o[6], o[7]);
    }
  } else {
    const float* wef = (const float*)we_raw + (size_t)(b*N + i)*N*BINW;
    for (int t4 = tid; t4 < N*BINW/4; t4 += 128)
      *(float4*)&wel[t4*4] = *(const float4*)&wef[t4*4];
  }
  __syncthreads();
  int j = tid;
  float wr[BINW];
  #pragma unroll
  for (int t = 0; t < BINW; ++t) wr[t] = wel[j*BINW + t];
  float wcon = 0.f;
  for (int o = 0; o < BOUT; ++o){
    float wp = R[O_WFCB + o];                 // uniform addresses -> scalarizable
    #pragma unroll
    for (int t = 0; t < BINW; ++t) wp += wr[t] * R[O_WFCW + t*BOUT + o];
    wcon += lrelu(wp) * R[O_FCW + EOUT + o];
  }
  float econ = (i < 64) ? R[O_SU + b*N + 2*i + (j >= 64 ? 1 : 0)]
                        : R[O_SV + b*N + j];
  float etot = econ + wcon + R[O_FCB];
  float m = (adj[(b*N + i)*N + j] > 0) ? etot : -9e15f;
  float mx = m;
  for (int off = 32; off; off >>= 1) mx = fmaxf(mx, __shfl_xor(mx, off));
  if ((tid & 63) == 0) red2[tid >> 6] = mx;
  __syncthreads();
  mx = fmaxf(red2[0], red2[1]);
  float ev = expf(m - mx);
  float sum = ev;
  for (int off = 32; off; off >>= 1) sum += __shfl_xor(sum, off);
  __syncthreads();
  if ((tid & 63) == 0) red2[tid >> 6] = sum;
  __syncthreads();
  sum = red2[0] + red2[1];
  float att = ev / sum;
  attl[j] = att;
  Wr[O_ATT + (b*N + i)*N + j] = att;
  float sbi = R[O_S + b*N + i];
  hnp[j] = lrelu(att * sbi + R[O_FCCB]);
  __syncthreads();
  {
    int d = tid >> 6, c = tid & 63;
    int wb = d ? O_WIHB : O_WIHF;
    float acc = R[(d ? O_BIHB : O_BIHF) + c] + R[(d ? O_BHHB : O_BHHF) + c];
    #pragma unroll 8
    for (int k = 0; k < N; k += 4){
      float4 h4 = *(const float4*)&hnp[k];
      float4 w4 = *(const float4*)&R[wb + c*N + k];
      acc += h4.x*w4.x + h4.y*w4.y + h4.z*w4.z + h4.w*w4.w;
    }
    Wr[(d ? O_ZB : O_ZF) + (b*N + i)*CI + c] = acc;
  }
}

// K4: recurrence — one wave per (dir,batch). Broadcast via BATCHED v_readlane
// (one SGPR-hazard boundary per step, no LDS round trip in the critical path).
__global__ __launch_bounds__(64, 1) void k_rnn(float* __restrict__ ws){
  int blk = blockIdx.x; int d = blk >> 4, b = blk & 15; int c = threadIdx.x;
  const int wb = d ? O_WHHB : O_WHHF;
  const int zb = (d ? O_ZB : O_ZF) + b*N*CI;
  const int ob = (d ? O_RB : O_RF) + b*N*CI;
  __shared__ __align__(16) float zo[N*CI];   // z in / h out (slot t dead after step t)
  float wreg[CI];
  #pragma unroll
  for (int k = 0; k < CI; k += 4){
    float4 w4 = *(const float4*)&ws[wb + c*CI + k];
    wreg[k]=w4.x; wreg[k+1]=w4.y; wreg[k+2]=w4.z; wreg[k+3]=w4.w;
  }
  for (int it = 0; it < N*CI/4; it += 64)
    *(float4*)&zo[(it + c)*4] = *(const float4*)&ws[zb + (it + c)*4];
  const int step = d ? -1 : 1;
  int tt = d ? (N-1) : 0;
  float hv = 0.f;
  float z = zo[tt*CI + c];        // single wave: DS ops in-order, no barrier needed
  for (int t = 0; t < N; ++t){
    int ti = tt + step; ti = ti < 0 ? 0 : (ti > N-1 ? N-1 : ti);
    float znext = zo[ti*CI + c];  // prefetch next step's z (slot untouched until its step)
    float s[CI];
    #pragma unroll
    for (int k = 0; k < CI; ++k) s[k] = bcastf(hv, k);   // 64 readlanes, batched
#if __has_builtin(__builtin_amdgcn_sched_barrier)
    __builtin_amdgcn_sched_barrier(0);                   // keep batch before FMAs
#endif
    float a0 = z, a1 = 0.f, a2 = 0.f, a3 = 0.f;
    #pragma unroll
    for (int k = 0; k < CI; k += 4){
      a0 = fmaf(s[k+0], wreg[k+0], a0);
      a1 = fmaf(s[k+1], wreg[k+1], a1);
      a2 = fmaf(s[k+2], wreg[k+2], a2);
      a3 = fmaf(s[k+3], wreg[k+3], a3);
    }
    float x = (a0+a1)+(a2+a3);
    x = fminf(15.f, fmaxf(-15.f, x));
    float p = __expf(2.f * x);
    hv = (p - 1.f) * __builtin_amdgcn_rcpf(p + 1.f);
    zo[tt*CI + c] = hv;
    z = znext;
    tt += step;
  }
  for (int it = 0; it < N*CI/4; it += 64)
    *(float4*)&ws[ob + (it + c)*4] = *(const float4*)&zo[(it + c)*4];
}

// K5: h1 = att @ h, 8 rows per block for h-tile reuse
__global__ __launch_bounds__(256) void k_h1(const float* __restrict__ R, float* __restrict__ Wr){
  int b = blockIdx.x >> 4, i0 = (blockIdx.x & 15) * 8;
  int f = threadIdx.x;
  __shared__ __align__(16) float attT[N*8];   // [k][r]
  for (int t = threadIdx.x; t < 8*N; t += 256){
    int r = t >> 7, k = t & 127;
    attT[k*8 + r] = R[O_ATT + (b*N + i0 + r)*N + k];
  }
  __syncthreads();
  float acc[8] = {0,0,0,0,0,0,0,0};
  for (int k = 0; k < N; ++k){
    float hv = R[O_H + (b*N + k)*FOUT + f];
    float4 a0 = *(const float4*)&attT[k*8];
    float4 a1 = *(const float4*)&attT[k*8 + 4];
    acc[0] += a0.x*hv; acc[1] += a0.y*hv; acc[2] += a0.z*hv; acc[3] += a0.w*hv;
    acc[4] += a1.x*hv; acc[5] += a1.y*hv; acc[6] += a1.z*hv; acc[7] += a1.w*hv;
  }
  #pragma unroll
  for (int r = 0; r < 8; ++r)
    Wr[O_H1 + (b*N + i0 + r)*FOUT + f] = acc[r];
}

// K6: out = elu(cat(lrelu(rnn_f), lrelu(rnn_b), h1) @ fco_w + fco_b), 4 rows/block
__global__ __launch_bounds__(256) void k_out(const void* __restrict__ x0,
                                             const float* __restrict__ R, void* dout){
  int blk = blockIdx.x, tid = threadIdx.x;
  int b = blk >> 5, i0 = (blk & 31) * 4;
  constexpr int KW = 2*CI + FOUT;  // 416
  __shared__ __align__(16) float inl[4*KW];
  __shared__ int smode;
  if (tid == 0) smode = detect_bf16(x0);
  for (int t = tid; t < 4*KW; t += 256){
    int r = t / KW, k = t % KW;
    int row = b*N + i0 + r;
    float v;
    if (k < CI)        v = lrelu(R[O_RF + row*CI + k]);
    else if (k < 2*CI) v = lrelu(R[O_RB + row*CI + (k - CI)]);
    else               v = R[O_H1 + row*FOUT + (k - 2*CI)];
    inl[t] = v;
  }
  __syncthreads();
  int l = tid;
  float bias = R[O_FCOB + l];
  float acc[4] = {bias, bias, bias, bias};
  for (int k = 0; k < KW; k += 4){
    float w0 = R[O_FCOW + (k+0)*L1 + l];
    float w1 = R[O_FCOW + (k+1)*L1 + l];
    float w2 = R[O_FCOW + (k+2)*L1 + l];
    float w3 = R[O_FCOW + (k+3)*L1 + l];
    #pragma unroll
    for (int r = 0; r < 4; ++r){
      float4 v = *(const float4*)&inl[r*KW + k];
      acc[r] += v.x*w0 + v.y*w1 + v.z*w2 + v.w*w3;
    }
  }
  int mode = smode;
  #pragma unroll
  for (int r = 0; r < 4; ++r){
    float o = acc[r] > 0.f ? acc[r] : expm1f(acc[r]);
    int idx = (b*N + i0 + r)*L1 + l;
    if (mode) ((__hip_bfloat16*)dout)[idx] = __float2bfloat16(o);
    else      ((float*)dout)[idx] = o;
  }
}

extern "C" void kernel_launch(void* const* d_in, const int* in_sizes, int n_in,
                              void* d_out, int out_size, void* d_ws, size_t ws_size,
                              hipStream_t stream){
  (void)in_sizes; (void)n_in; (void)out_size; (void)ws_size;
  float* ws = (float*)d_ws;
  ConvArgs ca;
  const int map[NCONV] = {3,4,5,6,7,8,9,10,11,12,13,14,15,16,17,18,19,20};
  for (int t = 0; t < NCONV; ++t) ca.p[t] = d_in[map[t]];
  hipLaunchKernelGGL(k_convert, dim3(128),  dim3(256), 0, stream, ca, d_in[0], ws);
  hipLaunchKernelGGL(k_h_pq,   dim3(256),  dim3(256), 0, stream, d_in[0], ws, ws);
  hipLaunchKernelGGL(k_susv,   dim3(B*N),  dim3(64),  0, stream, ws, ws);
  hipLaunchKernelGGL(k_att,    dim3(B*N),  dim3(128), 0, stream,
                     (const int*)d_in[1], d_in[2], d_in[0], ws, ws);
  hipLaunchKernelGGL(k_rnn,    dim3(32),   dim3(64),  0, stream, ws);
  hipLaunchKernelGGL(k_h1,     dim3(256),  dim3(256), 0, stream, ws, ws);
  hipLaunchKernelGGL(k_out,    dim3(B*N/4), dim3(256), 0, stream, d_in[0], ws, d_out);
}